// Round 1
// baseline (5130.597 us; speedup 1.0000x reference)
//
#include <hip/hip_runtime.h>
#include <hip/hip_bf16.h>
#include <math.h>

typedef unsigned short us;
typedef short bf16x8 __attribute__((ext_vector_type(8)));
typedef float f32x4 __attribute__((ext_vector_type(4)));
typedef unsigned short usx4 __attribute__((ext_vector_type(4)));

#define NT   2048   // B*T tokens
#define DDIM 1024
#define FF   4096
#define TT   1024
#define NH   16
#define CL   1023   // T - n_non_bias_tokens

__device__ __forceinline__ us f2bf(float f) {
  unsigned u = __float_as_uint(f);
  return (us)((u + 0x7FFFu + ((u >> 16) & 1u)) >> 16);
}

// ---------------- cast kernels ----------------
__device__ __forceinline__ void cast_seg(const float* s, us* d, int n4, int tid, int stride) {
  if (n4 <= 0) return;
  for (int i = tid; i < n4; i += stride) {
    float4 v = ((const float4*)s)[i];
    usx4 o; o.x = f2bf(v.x); o.y = f2bf(v.y); o.z = f2bf(v.z); o.w = f2bf(v.w);
    ((usx4*)d)[i] = o;
  }
}

__global__ void cast5_kernel(const float* s0, us* d0, int n0,
                             const float* s1, us* d1, int n1,
                             const float* s2, us* d2, int n2,
                             const float* s3, us* d3, int n3,
                             const float* s4, us* d4, int n4) {
  int tid = blockIdx.x * blockDim.x + threadIdx.x;
  int stride = gridDim.x * blockDim.x;
  cast_seg(s0, d0, n0, tid, stride);
  cast_seg(s1, d1, n1, tid, stride);
  cast_seg(s2, d2, n2, tid, stride);
  cast_seg(s3, d3, n3, tid, stride);
  cast_seg(s4, d4, n4, tid, stride);
}

__global__ void cast1_kernel(const float* s, us* d, int n4) {
  int tid = blockIdx.x * blockDim.x + threadIdx.x;
  int stride = gridDim.x * blockDim.x;
  cast_seg(s, d, n4, tid, stride);
}

// ---------------- MFMA GEMM: C[M,N] = A[M,K] @ W[N,K]^T ----------------
// MODE 0: outf = acc
// MODE 1: outf = acc + res
// MODE 2: outb = bf16(gelu(acc + bias))
// MODE 3: outf = acc + bias + res
// MODE 4: outf = acc + bias
template<int MODE, int WM, int WN>
__global__ __launch_bounds__(WM*WN*64)
void gemm_bt(const us* __restrict__ A, const us* __restrict__ W,
             const float* __restrict__ bias, const float* res,
             float* outf, us* outb, int M, int N, int K)
{
  constexpr int BM = WM * 64, BN = WN * 64, THREADS = WM * WN * 64;
  __shared__ us As[BM * 32];
  __shared__ us Ws[BN * 32];
  const int tid = threadIdx.x;
  const int m0 = blockIdx.y * BM, n0 = blockIdx.x * BN;
  const int wave = tid >> 6, lane = tid & 63;
  const int wm = (wave / WN) * 64, wn = (wave % WN) * 64;
  const int frow = lane & 15, fk = (lane >> 4) * 8;
  f32x4 acc[4][4] = {};
  for (int k0 = 0; k0 < K; k0 += 32) {
    #pragma unroll
    for (int e = tid * 8; e < BM * 32; e += THREADS * 8) {
      int r = e >> 5, c = e & 31;
      *(bf16x8*)(As + e) = *(const bf16x8*)(A + (size_t)(m0 + r) * K + k0 + c);
    }
    #pragma unroll
    for (int e = tid * 8; e < BN * 32; e += THREADS * 8) {
      int r = e >> 5, c = e & 31;
      *(bf16x8*)(Ws + e) = *(const bf16x8*)(W + (size_t)(n0 + r) * K + k0 + c);
    }
    __syncthreads();
    bf16x8 afr[4], wfr[4];
    #pragma unroll
    for (int i = 0; i < 4; ++i) afr[i] = *(const bf16x8*)(As + (wm + i * 16 + frow) * 32 + fk);
    #pragma unroll
    for (int i = 0; i < 4; ++i) wfr[i] = *(const bf16x8*)(Ws + (wn + i * 16 + frow) * 32 + fk);
    #pragma unroll
    for (int mi = 0; mi < 4; ++mi)
      #pragma unroll
      for (int ni = 0; ni < 4; ++ni)
        acc[mi][ni] = __builtin_amdgcn_mfma_f32_16x16x32_bf16(afr[mi], wfr[ni], acc[mi][ni], 0, 0, 0);
    __syncthreads();
  }
  // epilogue: C/D layout col=lane&15, row=(lane>>4)*4+reg  [measured m89/m91]
  const int col = lane & 15, rq = (lane >> 4) * 4;
  #pragma unroll
  for (int mi = 0; mi < 4; ++mi) {
    #pragma unroll
    for (int r = 0; r < 4; ++r) {
      int gm = m0 + wm + mi * 16 + rq + r;
      #pragma unroll
      for (int ni = 0; ni < 4; ++ni) {
        int gn = n0 + wn + ni * 16 + col;
        size_t oi = (size_t)gm * N + gn;
        float v = acc[mi][ni][r];
        if (MODE == 0) outf[oi] = v;
        if (MODE == 1) outf[oi] = v + res[oi];
        if (MODE == 2) {
          float tb = v + bias[gn];
          outb[oi] = f2bf(0.5f * tb * (1.0f + erff(tb * 0.70710678118654752f)));
        }
        if (MODE == 3) outf[oi] = v + bias[gn] + res[oi];
        if (MODE == 4) outf[oi] = v + bias[gn];
      }
    }
  }
}

// ---------------- qkv split: [NT,3072] -> Q/K/V [B,H,T,64], Q pre-scaled ----------------
__global__ void qkv_split_kernel(const float* __restrict__ qkv,
                                 float* __restrict__ Qh, float* __restrict__ Kh,
                                 float* __restrict__ Vh) {
  int i4 = blockIdx.x * blockDim.x + threadIdx.x;  // 524288 threads
  int e = i4 * 4;
  int d = e & 63;
  int t = (e >> 6) & (TT - 1);
  int h = (e >> 16) & (NH - 1);
  int b = e >> 20;
  const float* src = qkv + (size_t)(b * TT + t) * (3 * DDIM) + h * 64 + d;
  float4 q = *(const float4*)(src);
  float4 k = *(const float4*)(src + DDIM);
  float4 v = *(const float4*)(src + 2 * DDIM);
  q.x *= 0.125f; q.y *= 0.125f; q.z *= 0.125f; q.w *= 0.125f;
  ((float4*)Qh)[i4] = q;
  ((float4*)Kh)[i4] = k;
  ((float4*)Vh)[i4] = v;
}

// ---------------- fp32 vector flash attention (64-q tile, online softmax) ----------------
__global__ __launch_bounds__(256)
void attn_kernel(const float* __restrict__ Qh, const float* __restrict__ Kh,
                 const float* __restrict__ Vh, us* __restrict__ obf) {
  const int bh = blockIdx.y;
  const int h = bh & (NH - 1), b = bh >> 4;
  const int q0 = blockIdx.x * 64;
  const int t = threadIdx.x;
  __shared__ float Qs[64 * 65];
  __shared__ float KVs[64 * 65];   // holds K tile during S phase, V tile during PV
  __shared__ float Ps[64 * 65];
  __shared__ float part[4 * 64];
  __shared__ float mst[64], lst[64], alst[64];
  const float slope = -exp2f(-0.5f * (float)(h + 1));
  const size_t base = (size_t)bh * TT * 64;
  // Q tile fill (coalesced, pad-65 scalar LDS writes -> 2-way max)
  #pragma unroll
  for (int c = 0; c < 4; ++c) {
    int e4 = c * 256 + t;
    int row = e4 >> 4, colc = (e4 & 15) * 4;
    float4 v = *(const float4*)(Qh + base + (size_t)(q0 + row) * 64 + colc);
    float* dst = &Qs[row * 65 + colc];
    dst[0] = v.x; dst[1] = v.y; dst[2] = v.z; dst[3] = v.w;
  }
  if (t < 64) { mst[t] = -1e30f; lst[t] = 0.0f; }
  float O[4][4] = {};
  const int qg = t >> 4, kg = t & 15;
  __syncthreads();
  for (int kt = 0; kt < 16; ++kt) {
    const int k0 = kt * 64;
    // K tile fill
    #pragma unroll
    for (int c = 0; c < 4; ++c) {
      int e4 = c * 256 + t;
      int row = e4 >> 4, colc = (e4 & 15) * 4;
      float4 kv = *(const float4*)(Kh + base + (size_t)(k0 + row) * 64 + colc);
      float* kd = &KVs[row * 65 + colc];
      kd[0] = kv.x; kd[1] = kv.y; kd[2] = kv.z; kd[3] = kv.w;
    }
    __syncthreads();
    // S = Q@K^T (4x4 register block per thread)
    float sacc[4][4] = {};
    for (int d = 0; d < 64; ++d) {
      float qv[4], kv[4];
      #pragma unroll
      for (int i2 = 0; i2 < 4; ++i2) qv[i2] = Qs[(qg * 4 + i2) * 65 + d];
      #pragma unroll
      for (int j = 0; j < 4; ++j) kv[j] = KVs[(kg * 4 + j) * 65 + d];
      #pragma unroll
      for (int i2 = 0; i2 < 4; ++i2)
        #pragma unroll
        for (int j = 0; j < 4; ++j) sacc[i2][j] += qv[i2] * kv[j];
    }
    #pragma unroll
    for (int i2 = 0; i2 < 4; ++i2) {
      int qglob = q0 + qg * 4 + i2;
      #pragma unroll
      for (int j = 0; j < 4; ++j) {
        int kglob = k0 + kg * 4 + j;
        float ab = (qglob < CL && kglob < CL) ? slope * fabsf((float)(kglob - qglob)) : 0.0f;
        Ps[(qg * 4 + i2) * 65 + kg * 4 + j] = sacc[i2][j] + ab;
      }
    }
    __syncthreads();
    // row-max partials + V tile fill (K no longer needed)
    {
      int q = t & 63, qu = t >> 6;
      float m = -1e30f;
      #pragma unroll
      for (int c = 0; c < 16; ++c) m = fmaxf(m, Ps[q * 65 + qu * 16 + c]);
      part[qu * 64 + q] = m;
    }
    #pragma unroll
    for (int c = 0; c < 4; ++c) {
      int e4 = c * 256 + t;
      int row = e4 >> 4, colc = (e4 & 15) * 4;
      float4 vv = *(const float4*)(Vh + base + (size_t)(k0 + row) * 64 + colc);
      float* vd = &KVs[row * 65 + colc];
      vd[0] = vv.x; vd[1] = vv.y; vd[2] = vv.z; vd[3] = vv.w;
    }
    __syncthreads();
    if (t < 64) {
      float m = fmaxf(fmaxf(part[t], part[64 + t]), fmaxf(part[128 + t], part[192 + t]));
      float mnew = fmaxf(mst[t], m);
      alst[t] = expf(mst[t] - mnew);
      mst[t] = mnew;
    }
    __syncthreads();
    // P = exp(S - m_new), accumulate row sums
    {
      int q = t & 63, qu = t >> 6;
      float mnew = mst[q];
      float ssum = 0.0f;
      #pragma unroll
      for (int c = 0; c < 16; ++c) {
        int idx = q * 65 + qu * 16 + c;
        float pv = expf(Ps[idx] - mnew);
        Ps[idx] = pv;
        ssum += pv;
      }
      part[qu * 64 + q] = ssum;
    }
    __syncthreads();
    if (t < 64) lst[t] = alst[t] * lst[t] + part[t] + part[64 + t] + part[128 + t] + part[192 + t];
    // O = O*alpha + P@V
    {
      #pragma unroll
      for (int i2 = 0; i2 < 4; ++i2) {
        float a = alst[qg * 4 + i2];
        #pragma unroll
        for (int j = 0; j < 4; ++j) O[i2][j] *= a;
      }
      for (int k = 0; k < 64; ++k) {
        float pv[4], vv[4];
        #pragma unroll
        for (int i2 = 0; i2 < 4; ++i2) pv[i2] = Ps[(qg * 4 + i2) * 65 + k];
        #pragma unroll
        for (int j = 0; j < 4; ++j) vv[j] = KVs[k * 65 + kg * 4 + j];
        #pragma unroll
        for (int i2 = 0; i2 < 4; ++i2)
          #pragma unroll
          for (int j = 0; j < 4; ++j) O[i2][j] += pv[i2] * vv[j];
      }
    }
    __syncthreads();
  }
  #pragma unroll
  for (int i2 = 0; i2 < 4; ++i2) {
    float inv = 1.0f / lst[qg * 4 + i2];
    size_t token = (size_t)b * TT + q0 + qg * 4 + i2;
    #pragma unroll
    for (int j = 0; j < 4; ++j)
      obf[token * DDIM + h * 64 + kg * 4 + j] = f2bf(O[i2][j] * inv);
  }
}

// ---------------- LayerNorm (gain only, eps=1e-5), fp32 or bf16 out ----------------
template<int BF16OUT>
__global__ __launch_bounds__(256)
void ln_kernel(const float* __restrict__ x, const float* __restrict__ g,
               float* outf, us* outb) {
  __shared__ float red[256];
  const int rowi = blockIdx.x, t = threadIdx.x;
  const float* xr = x + (size_t)rowi * DDIM;
  float4 v = ((const float4*)xr)[t];
  red[t] = v.x + v.y + v.z + v.w;
  __syncthreads();
  for (int off = 128; off > 0; off >>= 1) {
    if (t < off) red[t] += red[t + off];
    __syncthreads();
  }
  float mu = red[0] * (1.0f / 1024.0f);
  __syncthreads();
  float dx = v.x - mu, dy = v.y - mu, dz = v.z - mu, dw = v.w - mu;
  red[t] = dx * dx + dy * dy + dz * dz + dw * dw;
  __syncthreads();
  for (int off = 128; off > 0; off >>= 1) {
    if (t < off) red[t] += red[t + off];
    __syncthreads();
  }
  float rs = rsqrtf(red[0] * (1.0f / 1024.0f) + 1e-5f);
  float4 gg = ((const float4*)g)[t];
  if (BF16OUT) {
    usx4 o;
    o.x = f2bf(dx * rs * gg.x); o.y = f2bf(dy * rs * gg.y);
    o.z = f2bf(dz * rs * gg.z); o.w = f2bf(dw * rs * gg.w);
    ((usx4*)(outb + (size_t)rowi * DDIM))[t] = o;
  } else {
    float4 o;
    o.x = dx * rs * gg.x; o.y = dy * rs * gg.y; o.z = dz * rs * gg.z; o.w = dw * rs * gg.w;
    ((float4*)(outf + (size_t)rowi * DDIM))[t] = o;
  }
}

// ---------------- concat [x, s*2^-0.5] -> bf16 [NT, 2048] ----------------
__global__ void concat_cast_kernel(const float* __restrict__ x, const float* __restrict__ s,
                                   us* __restrict__ out) {
  int i4 = blockIdx.x * blockDim.x + threadIdx.x;  // 1048576 threads
  int e = i4 * 4;
  int r = e >> 11, c = e & 2047;
  float4 v;
  if (c < DDIM) {
    v = *(const float4*)(x + (size_t)r * DDIM + c);
  } else {
    v = *(const float4*)(s + (size_t)r * DDIM + (c - DDIM));
    v.x *= 0.70710678118654752f; v.y *= 0.70710678118654752f;
    v.z *= 0.70710678118654752f; v.w *= 0.70710678118654752f;
  }
  usx4 o; o.x = f2bf(v.x); o.y = f2bf(v.y); o.z = f2bf(v.z); o.w = f2bf(v.w);
  ((usx4*)out)[i4] = o;
}

// ---------------- launch ----------------
extern "C" void kernel_launch(void* const* d_in, const int* in_sizes, int n_in,
                              void* d_out, int out_size, void* d_ws, size_t ws_size,
                              hipStream_t stream) {
  (void)in_sizes; (void)n_in; (void)out_size; (void)ws_size;
  const float* x_in       = (const float*)d_in[0];
  const float* attn_w     = (const float*)d_in[1];
  const float* attn_out_w = (const float*)d_in[2];
  const float* mlp_ln_g   = (const float*)d_in[3];
  const float* mlp_in_w   = (const float*)d_in[4];
  const float* mlp_in_b   = (const float*)d_in[5];
  const float* mlp_out_w  = (const float*)d_in[6];
  const float* mlp_out_b  = (const float*)d_in[7];
  const float* skip_w     = (const float*)d_in[8];
  const float* skip_b     = (const float*)d_in[9];
  const float* out_ln_g   = (const float*)d_in[10];

  char* p = (char*)d_ws;
  auto alloc = [&](size_t bytes) { char* r = p; p += (bytes + 255) & ~(size_t)255; return r; };
  float* xbuf = (float*)alloc((size_t)NT * DDIM * 4);
  float* qkvb = (float*)alloc((size_t)NT * 3 * DDIM * 4);
  float* Qh   = (float*)alloc((size_t)NT * DDIM * 4);
  float* Kh   = (float*)alloc((size_t)NT * DDIM * 4);
  float* Vh   = (float*)alloc((size_t)NT * DDIM * 4);
  float* conn = (float*)alloc((size_t)3 * NT * DDIM * 4);
  us* xbf  = (us*)alloc((size_t)NT * DDIM * 2);
  us* obf  = (us*)alloc((size_t)NT * DDIM * 2);
  us* hln  = (us*)alloc((size_t)NT * DDIM * 2);
  us* hbf  = (us*)alloc((size_t)NT * FF * 2);
  us* xcbf = (us*)alloc((size_t)NT * 2 * DDIM * 2);
  us* wqkv = (us*)alloc((size_t)3 * DDIM * DDIM * 2);
  us* wao  = (us*)alloc((size_t)DDIM * DDIM * 2);
  us* wmi  = (us*)alloc((size_t)FF * DDIM * 2);
  us* wmo  = (us*)alloc((size_t)DDIM * FF * 2);
  us* wsk  = (us*)alloc((size_t)DDIM * 2 * DDIM * 2);

  hipMemcpyAsync(xbuf, x_in, (size_t)NT * DDIM * 4, hipMemcpyDeviceToDevice, stream);

  for (int i = 0; i < 8; ++i) {
    const int do_skip = (i >= 5);
    cast5_kernel<<<1024, 256, 0, stream>>>(
        attn_w + (size_t)i * 3 * DDIM * DDIM, wqkv, 3 * DDIM * DDIM / 4,
        attn_out_w + (size_t)i * DDIM * DDIM, wao, DDIM * DDIM / 4,
        mlp_in_w + (size_t)i * FF * DDIM, wmi, FF * DDIM / 4,
        mlp_out_w + (size_t)i * DDIM * FF, wmo, DDIM * FF / 4,
        do_skip ? (skip_w + (size_t)(i - 4) * DDIM * 2 * DDIM) : nullptr, wsk,
        do_skip ? (DDIM * 2 * DDIM / 4) : 0);
    if (do_skip) {
      concat_cast_kernel<<<4096, 256, 0, stream>>>(xbuf, conn + (size_t)(7 - i) * NT * DDIM, xcbf);
      gemm_bt<4, 1, 2><<<dim3(DDIM / 128, NT / 64), 128, 0, stream>>>(
          xcbf, wsk, skip_b + (size_t)(i - 4) * DDIM, nullptr, xbuf, nullptr, NT, DDIM, 2 * DDIM);
    }
    cast1_kernel<<<1024, 256, 0, stream>>>(xbuf, xbf, NT * DDIM / 4);
    gemm_bt<0, 2, 2><<<dim3(3 * DDIM / 128, NT / 128), 256, 0, stream>>>(
        xbf, wqkv, nullptr, nullptr, qkvb, nullptr, NT, 3 * DDIM, DDIM);
    qkv_split_kernel<<<NT * DDIM / 4 / 256, 256, 0, stream>>>(qkvb, Qh, Kh, Vh);
    attn_kernel<<<dim3(TT / 64, 2 * NH), 256, 0, stream>>>(Qh, Kh, Vh, obf);
    gemm_bt<1, 1, 2><<<dim3(DDIM / 128, NT / 64), 128, 0, stream>>>(
        obf, wao, nullptr, xbuf, xbuf, nullptr, NT, DDIM, DDIM);
    ln_kernel<1><<<NT, 256, 0, stream>>>(xbuf, mlp_ln_g + (size_t)i * DDIM, nullptr, hln);
    gemm_bt<2, 2, 2><<<dim3(FF / 128, NT / 128), 256, 0, stream>>>(
        hln, wmi, mlp_in_b + (size_t)i * FF, nullptr, nullptr, hbf, NT, FF, DDIM);
    gemm_bt<3, 1, 2><<<dim3(DDIM / 128, NT / 64), 128, 0, stream>>>(
        hbf, wmo, mlp_out_b + (size_t)i * DDIM, xbuf, xbuf, nullptr, NT, DDIM, FF);
    if (i >= 2 && i <= 4)
      hipMemcpyAsync(conn + (size_t)(i - 2) * NT * DDIM, xbuf, (size_t)NT * DDIM * 4,
                     hipMemcpyDeviceToDevice, stream);
  }
  ln_kernel<0><<<NT, 256, 0, stream>>>(xbuf, out_ln_g, (float*)d_out, nullptr);
}

// Round 2
// 2503.497 us; speedup vs baseline: 2.0494x; 2.0494x over previous
//
#include <hip/hip_runtime.h>
#include <hip/hip_bf16.h>
#include <math.h>

typedef unsigned short us;
typedef short bf16x8 __attribute__((ext_vector_type(8)));
typedef float f32x4 __attribute__((ext_vector_type(4)));
typedef unsigned short usx4 __attribute__((ext_vector_type(4)));

#define NT   2048   // B*T tokens
#define DDIM 1024
#define FF   4096
#define TT   1024
#define NH   16
#define CL   1023   // T - n_non_bias_tokens

__device__ __forceinline__ us f2bf(float f) {
  unsigned u = __float_as_uint(f);
  return (us)((u + 0x7FFFu + ((u >> 16) & 1u)) >> 16);
}

// async global->LDS, 16B per lane; lds base must be wave-uniform [m97 pattern]
__device__ __forceinline__ void gld_lds16(const us* g, us* l) {
  __builtin_amdgcn_global_load_lds(
      (const __attribute__((address_space(1))) unsigned int*)(g),
      (__attribute__((address_space(3))) unsigned int*)(l), 16, 0, 0);
}

// ---------------- cast kernels ----------------
__device__ __forceinline__ void cast_seg(const float* s, us* d, int n4, int tid, int stride) {
  if (n4 <= 0) return;
  for (int i = tid; i < n4; i += stride) {
    float4 v = ((const float4*)s)[i];
    usx4 o; o.x = f2bf(v.x); o.y = f2bf(v.y); o.z = f2bf(v.z); o.w = f2bf(v.w);
    ((usx4*)d)[i] = o;
  }
}

__global__ void cast5_kernel(const float* s0, us* d0, int n0,
                             const float* s1, us* d1, int n1,
                             const float* s2, us* d2, int n2,
                             const float* s3, us* d3, int n3,
                             const float* s4, us* d4, int n4) {
  int tid = blockIdx.x * blockDim.x + threadIdx.x;
  int stride = gridDim.x * blockDim.x;
  cast_seg(s0, d0, n0, tid, stride);
  cast_seg(s1, d1, n1, tid, stride);
  cast_seg(s2, d2, n2, tid, stride);
  cast_seg(s3, d3, n3, tid, stride);
  cast_seg(s4, d4, n4, tid, stride);
}

__global__ void cast1_kernel(const float* s, us* d, int n4) {
  int tid = blockIdx.x * blockDim.x + threadIdx.x;
  int stride = gridDim.x * blockDim.x;
  cast_seg(s, d, n4, tid, stride);
}

// ---------------- MFMA GEMM: C[M,N] = A[M,K] @ W[N,K]^T ----------------
// MODE 0: outf = acc
// MODE 1: outf = acc + res
// MODE 2: outb = bf16(gelu(acc + bias))
// MODE 3: outf = acc + bias + res
// MODE 4: outf = acc + bias
template<int MODE, int WM, int WN>
__global__ __launch_bounds__(WM*WN*64)
void gemm_bt(const us* __restrict__ A, const us* __restrict__ W,
             const float* __restrict__ bias, const float* res,
             float* outf, us* outb, int M, int N, int K)
{
  constexpr int BM = WM * 64, BN = WN * 64, THREADS = WM * WN * 64;
  __shared__ us As[BM * 32];
  __shared__ us Ws[BN * 32];
  const int tid = threadIdx.x;
  const int m0 = blockIdx.y * BM, n0 = blockIdx.x * BN;
  const int wave = tid >> 6, lane = tid & 63;
  const int wm = (wave / WN) * 64, wn = (wave % WN) * 64;
  const int frow = lane & 15, fk = (lane >> 4) * 8;
  f32x4 acc[4][4] = {};
  for (int k0 = 0; k0 < K; k0 += 32) {
    // async staging: LDS linear order == lane order (no pad) [m97/m104 constraint]
    constexpr int APASS = (BM * 32) / (THREADS * 8);
    #pragma unroll
    for (int p = 0; p < APASS; ++p) {
      int linear = (p * THREADS + tid) * 8;
      int r = linear >> 5, c = linear & 31;
      gld_lds16(A + (size_t)(m0 + r) * K + k0 + c, As + (p * THREADS + wave * 64) * 8);
    }
    constexpr int WPASS = (BN * 32) / (THREADS * 8);
    #pragma unroll
    for (int p = 0; p < WPASS; ++p) {
      int linear = (p * THREADS + tid) * 8;
      int r = linear >> 5, c = linear & 31;
      gld_lds16(W + (size_t)(n0 + r) * K + k0 + c, Ws + (p * THREADS + wave * 64) * 8);
    }
    __syncthreads();
    bf16x8 afr[4], wfr[4];
    #pragma unroll
    for (int i = 0; i < 4; ++i) afr[i] = *(const bf16x8*)(As + (wm + i * 16 + frow) * 32 + fk);
    #pragma unroll
    for (int i = 0; i < 4; ++i) wfr[i] = *(const bf16x8*)(Ws + (wn + i * 16 + frow) * 32 + fk);
    #pragma unroll
    for (int mi = 0; mi < 4; ++mi)
      #pragma unroll
      for (int ni = 0; ni < 4; ++ni)
        acc[mi][ni] = __builtin_amdgcn_mfma_f32_16x16x32_bf16(afr[mi], wfr[ni], acc[mi][ni], 0, 0, 0);
    __syncthreads();
  }
  // epilogue: C/D layout col=lane&15, row=(lane>>4)*4+reg  [measured m89/m91]
  const int col = lane & 15, rq = (lane >> 4) * 4;
  #pragma unroll
  for (int mi = 0; mi < 4; ++mi) {
    #pragma unroll
    for (int r = 0; r < 4; ++r) {
      int gm = m0 + wm + mi * 16 + rq + r;
      #pragma unroll
      for (int ni = 0; ni < 4; ++ni) {
        int gn = n0 + wn + ni * 16 + col;
        size_t oi = (size_t)gm * N + gn;
        float v = acc[mi][ni][r];
        if (MODE == 0) outf[oi] = v;
        if (MODE == 1) outf[oi] = v + res[oi];
        if (MODE == 2) {
          float tb = v + bias[gn];
          outb[oi] = f2bf(0.5f * tb * (1.0f + erff(tb * 0.70710678118654752f)));
        }
        if (MODE == 3) outf[oi] = v + bias[gn] + res[oi];
        if (MODE == 4) outf[oi] = v + bias[gn];
      }
    }
  }
}

// ---------------- qkv prep: fp32 qkv [NT,3072] -> Qb,Kb bf16 [b,h,t,d] (Q*0.125),
//                  Vt bf16 [b,h,d,t] (transposed via LDS) ----------------
__global__ __launch_bounds__(256)
void qkvprep_kernel(const float* __restrict__ qkv, us* __restrict__ Qb,
                    us* __restrict__ Kb, us* __restrict__ Vt) {
  __shared__ float Vtile[64 * 65];
  const int bh = blockIdx.y;
  const int h = bh & (NH - 1), b = bh >> 4;
  const int t0 = blockIdx.x * 64;
  const int tid = threadIdx.x;
  const size_t kvbase = (size_t)bh * TT * 64;
  const size_t vtbase = (size_t)bh * 64 * TT;
  #pragma unroll
  for (int p = 0; p < 4; ++p) {
    int e4 = p * 256 + tid;                 // 1024 float4 = 64t x 64d
    int trow = e4 >> 4, dcol = (e4 & 15) * 4;
    const float* src = qkv + (size_t)(b * TT + t0 + trow) * (3 * DDIM) + h * 64 + dcol;
    float4 q = *(const float4*)(src);
    float4 k = *(const float4*)(src + DDIM);
    float4 v = *(const float4*)(src + 2 * DDIM);
    usx4 qo; qo.x = f2bf(q.x * 0.125f); qo.y = f2bf(q.y * 0.125f);
    qo.z = f2bf(q.z * 0.125f); qo.w = f2bf(q.w * 0.125f);
    usx4 ko; ko.x = f2bf(k.x); ko.y = f2bf(k.y); ko.z = f2bf(k.z); ko.w = f2bf(k.w);
    *(usx4*)(Qb + kvbase + (size_t)(t0 + trow) * 64 + dcol) = qo;
    *(usx4*)(Kb + kvbase + (size_t)(t0 + trow) * 64 + dcol) = ko;
    float* vd = &Vtile[trow * 65 + dcol];
    vd[0] = v.x; vd[1] = v.y; vd[2] = v.z; vd[3] = v.w;
  }
  __syncthreads();
  #pragma unroll
  for (int p = 0; p < 4; ++p) {
    int d = p * 16 + (tid >> 4);
    int c = tid & 15;                        // t-chunk of 4
    usx4 o;
    o.x = f2bf(Vtile[(c * 4 + 0) * 65 + d]);
    o.y = f2bf(Vtile[(c * 4 + 1) * 65 + d]);
    o.z = f2bf(Vtile[(c * 4 + 2) * 65 + d]);
    o.w = f2bf(Vtile[(c * 4 + 3) * 65 + d]);
    *(usx4*)(Vt + vtbase + (size_t)d * TT + t0 + c * 4) = o;
  }
}

// ---------------- MFMA flash attention ----------------
// block: 256 thr (4 waves), one (b,h), 64 q rows; wave w owns q rows [q0+16w, +16)
__global__ __launch_bounds__(256)
void attn_mfma_kernel(const us* __restrict__ Qb, const us* __restrict__ Kb,
                      const us* __restrict__ Vt, us* __restrict__ obf) {
  __shared__ us Ks[64 * 72];       // [key][d], pad 72
  __shared__ us Vs[64 * 72];       // [d][key], pad 72
  __shared__ us Ps[4][16 * 72];    // per-wave P [q][key]
  const int bh = blockIdx.y;
  const int h = bh & (NH - 1), b = bh >> 4;
  const int q0 = blockIdx.x * 64;
  const int tid = threadIdx.x, wave = tid >> 6, lane = tid & 63;
  const float slope = -exp2f(-0.5f * (float)(h + 1));
  const size_t kvbase = (size_t)bh * TT * 64;
  const size_t vtbase = (size_t)bh * 64 * TT;
  const int col = lane & 15, grp = lane >> 4, rq = grp * 4;
  const int qbase = q0 + wave * 16;
  us* Psw = Ps[wave];
  // Q A-fragments: A[m=lane&15][k=grp*8+j], d in {0..31, 32..63}
  bf16x8 qfrag[2];
  {
    const us* qp = Qb + kvbase + (size_t)(qbase + col) * 64 + grp * 8;
    qfrag[0] = *(const bf16x8*)(qp);
    qfrag[1] = *(const bf16x8*)(qp + 32);
  }
  f32x4 Oacc[4] = {};   // O[q=rq+r][d=ni*16+col]
  float mrow[4], lrow[4];
  #pragma unroll
  for (int r = 0; r < 4; ++r) { mrow[r] = -3e38f; lrow[r] = 0.0f; }
  for (int kt = 0; kt < 16; ++kt) {
    const int k0 = kt * 64;
    __syncthreads();   // prior iter's K/V reads complete before overwrite
    #pragma unroll
    for (int p = 0; p < 2; ++p) {
      int idx = tid * 8 + p * 2048;
      int r = idx >> 6, c = idx & 63;
      *(bf16x8*)(Ks + r * 72 + c) = *(const bf16x8*)(Kb + kvbase + (size_t)(k0 + r) * 64 + c);
      *(bf16x8*)(Vs + r * 72 + c) = *(const bf16x8*)(Vt + vtbase + (size_t)r * TT + k0 + c);
    }
    __syncthreads();
    // S = Q K^T  (keys = ni*16+col)
    f32x4 sacc[4];
    #pragma unroll
    for (int ni = 0; ni < 4; ++ni) {
      const us* kp = Ks + (ni * 16 + col) * 72 + grp * 8;
      bf16x8 kf0 = *(const bf16x8*)(kp);
      bf16x8 kf1 = *(const bf16x8*)(kp + 32);
      f32x4 a = {};
      a = __builtin_amdgcn_mfma_f32_16x16x32_bf16(qfrag[0], kf0, a, 0, 0, 0);
      a = __builtin_amdgcn_mfma_f32_16x16x32_bf16(qfrag[1], kf1, a, 0, 0, 0);
      sacc[ni] = a;
    }
    // + alibi, row max
    float pmax[4];
    #pragma unroll
    for (int r = 0; r < 4; ++r) pmax[r] = -3e38f;
    #pragma unroll
    for (int ni = 0; ni < 4; ++ni) {
      int kglob = k0 + ni * 16 + col;
      #pragma unroll
      for (int r = 0; r < 4; ++r) {
        int qglob = qbase + rq + r;
        float ab = (qglob < CL && kglob < CL) ? slope * fabsf((float)(kglob - qglob)) : 0.0f;
        sacc[ni][r] += ab;
        pmax[r] = fmaxf(pmax[r], sacc[ni][r]);
      }
    }
    #pragma unroll
    for (int off = 1; off < 16; off <<= 1)
      #pragma unroll
      for (int r = 0; r < 4; ++r)
        pmax[r] = fmaxf(pmax[r], __shfl_xor(pmax[r], off, 64));
    float alpha[4], psum[4];
    #pragma unroll
    for (int r = 0; r < 4; ++r) {
      float mnew = fmaxf(mrow[r], pmax[r]);
      alpha[r] = __expf(mrow[r] - mnew);
      mrow[r] = mnew;
      psum[r] = 0.0f;
    }
    // P = exp(S-m) -> per-wave LDS [q][key] (C-layout -> A-layout transform, m120)
    #pragma unroll
    for (int ni = 0; ni < 4; ++ni)
      #pragma unroll
      for (int r = 0; r < 4; ++r) {
        float pv = __expf(sacc[ni][r] - mrow[r]);
        psum[r] += pv;
        Psw[(rq + r) * 72 + ni * 16 + col] = f2bf(pv);
      }
    #pragma unroll
    for (int off = 1; off < 16; off <<= 1)
      #pragma unroll
      for (int r = 0; r < 4; ++r)
        psum[r] += __shfl_xor(psum[r], off, 64);
    #pragma unroll
    for (int r = 0; r < 4; ++r) lrow[r] = alpha[r] * lrow[r] + psum[r];
    // O = O*alpha + P V
    #pragma unroll
    for (int ni = 0; ni < 4; ++ni)
      #pragma unroll
      for (int r = 0; r < 4; ++r) Oacc[ni][r] *= alpha[r];
    bf16x8 pf0 = *(const bf16x8*)(Psw + col * 72 + grp * 8);
    bf16x8 pf1 = *(const bf16x8*)(Psw + col * 72 + 32 + grp * 8);
    #pragma unroll
    for (int ni = 0; ni < 4; ++ni) {
      const us* vp = Vs + (ni * 16 + col) * 72 + grp * 8;
      bf16x8 vf0 = *(const bf16x8*)(vp);
      bf16x8 vf1 = *(const bf16x8*)(vp + 32);
      Oacc[ni] = __builtin_amdgcn_mfma_f32_16x16x32_bf16(pf0, vf0, Oacc[ni], 0, 0, 0);
      Oacc[ni] = __builtin_amdgcn_mfma_f32_16x16x32_bf16(pf1, vf1, Oacc[ni], 0, 0, 0);
    }
  }
  #pragma unroll
  for (int ni = 0; ni < 4; ++ni)
    #pragma unroll
    for (int r = 0; r < 4; ++r) {
      size_t token = (size_t)b * TT + qbase + rq + r;
      obf[token * DDIM + h * 64 + ni * 16 + col] = f2bf(Oacc[ni][r] / lrow[r]);
    }
}

// ---------------- LayerNorm (gain only, eps=1e-5), fp32 or bf16 out ----------------
template<int BF16OUT>
__global__ __launch_bounds__(256)
void ln_kernel(const float* __restrict__ x, const float* __restrict__ g,
               float* outf, us* outb) {
  __shared__ float red[256];
  const int rowi = blockIdx.x, t = threadIdx.x;
  const float* xr = x + (size_t)rowi * DDIM;
  float4 v = ((const float4*)xr)[t];
  red[t] = v.x + v.y + v.z + v.w;
  __syncthreads();
  for (int off = 128; off > 0; off >>= 1) {
    if (t < off) red[t] += red[t + off];
    __syncthreads();
  }
  float mu = red[0] * (1.0f / 1024.0f);
  __syncthreads();
  float dx = v.x - mu, dy = v.y - mu, dz = v.z - mu, dw = v.w - mu;
  red[t] = dx * dx + dy * dy + dz * dz + dw * dw;
  __syncthreads();
  for (int off = 128; off > 0; off >>= 1) {
    if (t < off) red[t] += red[t + off];
    __syncthreads();
  }
  float rs = rsqrtf(red[0] * (1.0f / 1024.0f) + 1e-5f);
  float4 gg = ((const float4*)g)[t];
  if (BF16OUT) {
    usx4 o;
    o.x = f2bf(dx * rs * gg.x); o.y = f2bf(dy * rs * gg.y);
    o.z = f2bf(dz * rs * gg.z); o.w = f2bf(dw * rs * gg.w);
    ((usx4*)(outb + (size_t)rowi * DDIM))[t] = o;
  } else {
    float4 o;
    o.x = dx * rs * gg.x; o.y = dy * rs * gg.y; o.z = dz * rs * gg.z; o.w = dw * rs * gg.w;
    ((float4*)(outf + (size_t)rowi * DDIM))[t] = o;
  }
}

// ---------------- concat [x, s*2^-0.5] -> bf16 [NT, 2048] ----------------
__global__ void concat_cast_kernel(const float* __restrict__ x, const float* __restrict__ s,
                                   us* __restrict__ out) {
  int i4 = blockIdx.x * blockDim.x + threadIdx.x;  // 1048576 threads
  int e = i4 * 4;
  int r = e >> 11, c = e & 2047;
  float4 v;
  if (c < DDIM) {
    v = *(const float4*)(x + (size_t)r * DDIM + c);
  } else {
    v = *(const float4*)(s + (size_t)r * DDIM + (c - DDIM));
    v.x *= 0.70710678118654752f; v.y *= 0.70710678118654752f;
    v.z *= 0.70710678118654752f; v.w *= 0.70710678118654752f;
  }
  usx4 o; o.x = f2bf(v.x); o.y = f2bf(v.y); o.z = f2bf(v.z); o.w = f2bf(v.w);
  ((usx4*)out)[i4] = o;
}

// ---------------- launch ----------------
extern "C" void kernel_launch(void* const* d_in, const int* in_sizes, int n_in,
                              void* d_out, int out_size, void* d_ws, size_t ws_size,
                              hipStream_t stream) {
  (void)in_sizes; (void)n_in; (void)out_size; (void)ws_size;
  const float* x_in       = (const float*)d_in[0];
  const float* attn_w     = (const float*)d_in[1];
  const float* attn_out_w = (const float*)d_in[2];
  const float* mlp_ln_g   = (const float*)d_in[3];
  const float* mlp_in_w   = (const float*)d_in[4];
  const float* mlp_in_b   = (const float*)d_in[5];
  const float* mlp_out_w  = (const float*)d_in[6];
  const float* mlp_out_b  = (const float*)d_in[7];
  const float* skip_w     = (const float*)d_in[8];
  const float* skip_b     = (const float*)d_in[9];
  const float* out_ln_g   = (const float*)d_in[10];

  char* p = (char*)d_ws;
  auto alloc = [&](size_t bytes) { char* r = p; p += (bytes + 255) & ~(size_t)255; return r; };
  float* xbuf = (float*)alloc((size_t)NT * DDIM * 4);
  float* qkvb = (float*)alloc((size_t)NT * 3 * DDIM * 4);
  float* conn = (float*)alloc((size_t)3 * NT * DDIM * 4);
  us* Qb   = (us*)alloc((size_t)NT * DDIM * 2);
  us* Kb   = (us*)alloc((size_t)NT * DDIM * 2);
  us* Vt   = (us*)alloc((size_t)NT * DDIM * 2);
  us* xbf  = (us*)alloc((size_t)NT * DDIM * 2);
  us* obf  = (us*)alloc((size_t)NT * DDIM * 2);
  us* hln  = (us*)alloc((size_t)NT * DDIM * 2);
  us* hbf  = (us*)alloc((size_t)NT * FF * 2);
  us* xcbf = (us*)alloc((size_t)NT * 2 * DDIM * 2);
  us* wqkv = (us*)alloc((size_t)3 * DDIM * DDIM * 2);
  us* wao  = (us*)alloc((size_t)DDIM * DDIM * 2);
  us* wmi  = (us*)alloc((size_t)FF * DDIM * 2);
  us* wmo  = (us*)alloc((size_t)DDIM * FF * 2);
  us* wsk  = (us*)alloc((size_t)DDIM * 2 * DDIM * 2);

  hipMemcpyAsync(xbuf, x_in, (size_t)NT * DDIM * 4, hipMemcpyDeviceToDevice, stream);

  for (int i = 0; i < 8; ++i) {
    const int do_skip = (i >= 5);
    cast5_kernel<<<1024, 256, 0, stream>>>(
        attn_w + (size_t)i * 3 * DDIM * DDIM, wqkv, 3 * DDIM * DDIM / 4,
        attn_out_w + (size_t)i * DDIM * DDIM, wao, DDIM * DDIM / 4,
        mlp_in_w + (size_t)i * FF * DDIM, wmi, FF * DDIM / 4,
        mlp_out_w + (size_t)i * DDIM * FF, wmo, DDIM * FF / 4,
        do_skip ? (skip_w + (size_t)(i - 4) * DDIM * 2 * DDIM) : nullptr, wsk,
        do_skip ? (DDIM * 2 * DDIM / 4) : 0);
    if (do_skip) {
      concat_cast_kernel<<<4096, 256, 0, stream>>>(xbuf, conn + (size_t)(7 - i) * NT * DDIM, xcbf);
      gemm_bt<4, 1, 2><<<dim3(DDIM / 128, NT / 64), 128, 0, stream>>>(
          xcbf, wsk, skip_b + (size_t)(i - 4) * DDIM, nullptr, xbuf, nullptr, NT, DDIM, 2 * DDIM);
    }
    cast1_kernel<<<1024, 256, 0, stream>>>(xbuf, xbf, NT * DDIM / 4);
    gemm_bt<0, 2, 2><<<dim3(3 * DDIM / 128, NT / 128), 256, 0, stream>>>(
        xbf, wqkv, nullptr, nullptr, qkvb, nullptr, NT, 3 * DDIM, DDIM);
    qkvprep_kernel<<<dim3(TT / 64, 2 * NH), 256, 0, stream>>>(qkvb, Qb, Kb, Vt);
    attn_mfma_kernel<<<dim3(TT / 64, 2 * NH), 256, 0, stream>>>(Qb, Kb, Vt, obf);
    gemm_bt<1, 1, 2><<<dim3(DDIM / 128, NT / 64), 128, 0, stream>>>(
        obf, wao, nullptr, xbuf, xbuf, nullptr, NT, DDIM, DDIM);
    ln_kernel<1><<<NT, 256, 0, stream>>>(xbuf, mlp_ln_g + (size_t)i * DDIM, nullptr, hln);
    gemm_bt<2, 2, 2><<<dim3(FF / 128, NT / 128), 256, 0, stream>>>(
        hln, wmi, mlp_in_b + (size_t)i * FF, nullptr, nullptr, hbf, NT, FF, DDIM);
    gemm_bt<3, 1, 2><<<dim3(DDIM / 128, NT / 64), 128, 0, stream>>>(
        hbf, wmo, mlp_out_b + (size_t)i * DDIM, xbuf, xbuf, nullptr, NT, DDIM, FF);
    if (i >= 2 && i <= 4)
      hipMemcpyAsync(conn + (size_t)(i - 2) * NT * DDIM, xbuf, (size_t)NT * DDIM * 4,
                     hipMemcpyDeviceToDevice, stream);
  }
  ln_kernel<0><<<NT, 256, 0, stream>>>(xbuf, out_ln_g, (float*)d_out, nullptr);
}

// Round 3
// 2034.319 us; speedup vs baseline: 2.5220x; 1.2306x over previous
//
#include <hip/hip_runtime.h>
#include <hip/hip_bf16.h>
#include <math.h>

typedef unsigned short us;
typedef short bf16x8 __attribute__((ext_vector_type(8)));
typedef float f32x4 __attribute__((ext_vector_type(4)));
typedef unsigned short usx4 __attribute__((ext_vector_type(4)));

#define NT   2048   // B*T tokens
#define DDIM 1024
#define FF   4096
#define TT   1024
#define NH   16
#define CL   1023   // T - n_non_bias_tokens

__device__ __forceinline__ us f2bf(float f) {
  unsigned u = __float_as_uint(f);
  return (us)((u + 0x7FFFu + ((u >> 16) & 1u)) >> 16);
}

// async global->LDS, 16B per lane; lds base must be wave-uniform [m97 pattern]
__device__ __forceinline__ void gld_lds16(const us* g, us* l) {
  __builtin_amdgcn_global_load_lds(
      (const __attribute__((address_space(1))) unsigned int*)(g),
      (__attribute__((address_space(3))) unsigned int*)(l), 16, 0, 0);
}

// ---------------- cast kernels ----------------
__device__ __forceinline__ void cast_seg(const float* s, us* d, int n4, int tid, int stride) {
  if (n4 <= 0) return;
  for (int i = tid; i < n4; i += stride) {
    float4 v = ((const float4*)s)[i];
    usx4 o; o.x = f2bf(v.x); o.y = f2bf(v.y); o.z = f2bf(v.z); o.w = f2bf(v.w);
    ((usx4*)d)[i] = o;
  }
}

__global__ void cast5_kernel(const float* s0, us* d0, int n0,
                             const float* s1, us* d1, int n1,
                             const float* s2, us* d2, int n2,
                             const float* s3, us* d3, int n3,
                             const float* s4, us* d4, int n4) {
  int tid = blockIdx.x * blockDim.x + threadIdx.x;
  int stride = gridDim.x * blockDim.x;
  cast_seg(s0, d0, n0, tid, stride);
  cast_seg(s1, d1, n1, tid, stride);
  cast_seg(s2, d2, n2, tid, stride);
  cast_seg(s3, d3, n3, tid, stride);
  cast_seg(s4, d4, n4, tid, stride);
}

__global__ void cast1_kernel(const float* s, us* d, int n4) {
  int tid = blockIdx.x * blockDim.x + threadIdx.x;
  int stride = gridDim.x * blockDim.x;
  cast_seg(s, d, n4, tid, stride);
}

// ---------------- row-broadcast bias init: x = bias (SET=1) or x += bias ----------------
template<int SET>
__global__ void bias_rows_kernel(float* __restrict__ x, const float* __restrict__ bias) {
  int i = blockIdx.x * blockDim.x + threadIdx.x;    // over NT*DDIM/4 float4s
  float4 b = ((const float4*)bias)[i & 255];
  if (SET) {
    ((float4*)x)[i] = b;
  } else {
    float4 v = ((float4*)x)[i];
    v.x += b.x; v.y += b.y; v.z += b.z; v.w += b.w;
    ((float4*)x)[i] = v;
  }
}

// ---------------- 4-wave MFMA GEMM: C[M,N](partial) = A[M,K-chunk] @ W[N,K-chunk]^T ----
// block: 256 thr, BM=64, BN=128, wave tile 32x64; blockIdx.z = K-split index.
// MODE 2: outb = bf16(gelu(acc + bias))          (full K in one chunk)
// MODE 5: QKV fused epilogue -> Qb/Kb (bhtd, Q*0.125), Vt (bhdt)  (full K)
// MODE 6: atomicAdd(outf, acc)                   (split-K partials)
template<int MODE>
__global__ __launch_bounds__(256)
void gemm4(const us* __restrict__ A, const us* __restrict__ W,
           const float* __restrict__ bias, float* outf, us* outb,
           us* __restrict__ Qb, us* __restrict__ Kb, us* __restrict__ Vt,
           int M, int N, int K, int kchunk)
{
  __shared__ us As[64 * 32];
  __shared__ us Ws[128 * 32];
  const int tid = threadIdx.x;
  const int m0 = blockIdx.y * 64, n0 = blockIdx.x * 128;
  const int wave = tid >> 6, lane = tid & 63;
  const int wm = (wave & 1) * 32, wn = (wave >> 1) * 64;
  const int frow = lane & 15, fk = (lane >> 4) * 8;
  const int kbeg = blockIdx.z * kchunk, kend = kbeg + kchunk;
  const int ar = tid >> 2, ac = (tid & 3) * 8;      // A stage: row tid/4, col-8chunk
  const int wr1 = (256 + tid) >> 2;
  f32x4 acc[2][4] = {};
  for (int k0 = kbeg; k0 < kend; k0 += 32) {
    // staging: LDS linear order == lane order (wave-uniform base, m97/m104)
    gld_lds16(A + (size_t)(m0 + ar) * K + k0 + ac, As + wave * 512);
    gld_lds16(W + (size_t)(n0 + ar) * K + k0 + ac, Ws + wave * 512);
    gld_lds16(W + (size_t)(n0 + wr1) * K + k0 + ac, Ws + 2048 + wave * 512);
    __syncthreads();
    bf16x8 afr[2], wfr[4];
    #pragma unroll
    for (int i = 0; i < 2; ++i) afr[i] = *(const bf16x8*)(As + (wm + i * 16 + frow) * 32 + fk);
    #pragma unroll
    for (int j = 0; j < 4; ++j) wfr[j] = *(const bf16x8*)(Ws + (wn + j * 16 + frow) * 32 + fk);
    #pragma unroll
    for (int i = 0; i < 2; ++i)
      #pragma unroll
      for (int j = 0; j < 4; ++j)
        acc[i][j] = __builtin_amdgcn_mfma_f32_16x16x32_bf16(afr[i], wfr[j], acc[i][j], 0, 0, 0);
    __syncthreads();
  }
  // epilogue: C/D layout col=lane&15, row=(lane>>4)*4+reg [m89/m91]
  const int col = lane & 15, rq = (lane >> 4) * 4;
  #pragma unroll
  for (int i = 0; i < 2; ++i) {
    const int gmq = m0 + wm + i * 16 + rq;   // first of 4 consecutive token rows
    #pragma unroll
    for (int j = 0; j < 4; ++j) {
      const int gn = n0 + wn + j * 16 + col;
      if (MODE == 5) {
        const int t = gmq & (TT - 1), b = gmq >> 10;   // BM=64 tile never straddles batch
        if (gn < DDIM) {
          const int h = gn >> 6, d = gn & 63;
          us* qp = Qb + ((size_t)(b * NH + h) * TT + t) * 64 + d;
          #pragma unroll
          for (int r = 0; r < 4; ++r) qp[(size_t)r * 64] = f2bf(acc[i][j][r] * 0.125f);
        } else if (gn < 2 * DDIM) {
          const int h = (gn - DDIM) >> 6, d = gn & 63;
          us* kp = Kb + ((size_t)(b * NH + h) * TT + t) * 64 + d;
          #pragma unroll
          for (int r = 0; r < 4; ++r) kp[(size_t)r * 64] = f2bf(acc[i][j][r]);
        } else {
          const int h = (gn - 2 * DDIM) >> 6, d = gn & 63;
          usx4 o;
          o.x = f2bf(acc[i][j][0]); o.y = f2bf(acc[i][j][1]);
          o.z = f2bf(acc[i][j][2]); o.w = f2bf(acc[i][j][3]);
          *(usx4*)(Vt + ((size_t)(b * NH + h) * 64 + d) * TT + t) = o;
        }
      } else {
        #pragma unroll
        for (int r = 0; r < 4; ++r) {
          const size_t oi = (size_t)(gmq + r) * N + gn;
          float v = acc[i][j][r];
          if (MODE == 2) {
            float tb = v + bias[gn];
            outb[oi] = f2bf(0.5f * tb * (1.0f + erff(tb * 0.70710678118654752f)));
          }
          if (MODE == 6) atomicAdd(outf + oi, v);
        }
      }
    }
  }
}

// ---------------- MFMA flash attention ----------------
// block: 256 thr (4 waves), one (b,h), 64 q rows; wave w owns q rows [q0+16w, +16)
__global__ __launch_bounds__(256)
void attn_mfma_kernel(const us* __restrict__ Qb, const us* __restrict__ Kb,
                      const us* __restrict__ Vt, us* __restrict__ obf) {
  __shared__ us Ks[64 * 72];       // [key][d], pad 72
  __shared__ us Vs[64 * 72];       // [d][key], pad 72
  __shared__ us Ps[4][16 * 72];    // per-wave P [q][key]
  const int bh = blockIdx.y;
  const int h = bh & (NH - 1), b = bh >> 4;
  const int q0 = blockIdx.x * 64;
  const int tid = threadIdx.x, wave = tid >> 6, lane = tid & 63;
  const float slope = -exp2f(-0.5f * (float)(h + 1));
  const size_t kvbase = (size_t)bh * TT * 64;
  const size_t vtbase = (size_t)bh * 64 * TT;
  const int col = lane & 15, grp = lane >> 4, rq = grp * 4;
  const int qbase = q0 + wave * 16;
  us* Psw = Ps[wave];
  bf16x8 qfrag[2];
  {
    const us* qp = Qb + kvbase + (size_t)(qbase + col) * 64 + grp * 8;
    qfrag[0] = *(const bf16x8*)(qp);
    qfrag[1] = *(const bf16x8*)(qp + 32);
  }
  f32x4 Oacc[4] = {};   // O[q=rq+r][d=ni*16+col]
  float mrow[4], lrow[4];
  #pragma unroll
  for (int r = 0; r < 4; ++r) { mrow[r] = -3e38f; lrow[r] = 0.0f; }
  for (int kt = 0; kt < 16; ++kt) {
    const int k0 = kt * 64;
    __syncthreads();
    #pragma unroll
    for (int p = 0; p < 2; ++p) {
      int idx = tid * 8 + p * 2048;
      int r = idx >> 6, c = idx & 63;
      *(bf16x8*)(Ks + r * 72 + c) = *(const bf16x8*)(Kb + kvbase + (size_t)(k0 + r) * 64 + c);
      *(bf16x8*)(Vs + r * 72 + c) = *(const bf16x8*)(Vt + vtbase + (size_t)r * TT + k0 + c);
    }
    __syncthreads();
    f32x4 sacc[4];
    #pragma unroll
    for (int ni = 0; ni < 4; ++ni) {
      const us* kp = Ks + (ni * 16 + col) * 72 + grp * 8;
      bf16x8 kf0 = *(const bf16x8*)(kp);
      bf16x8 kf1 = *(const bf16x8*)(kp + 32);
      f32x4 a = {};
      a = __builtin_amdgcn_mfma_f32_16x16x32_bf16(qfrag[0], kf0, a, 0, 0, 0);
      a = __builtin_amdgcn_mfma_f32_16x16x32_bf16(qfrag[1], kf1, a, 0, 0, 0);
      sacc[ni] = a;
    }
    float pmax[4];
    #pragma unroll
    for (int r = 0; r < 4; ++r) pmax[r] = -3e38f;
    #pragma unroll
    for (int ni = 0; ni < 4; ++ni) {
      int kglob = k0 + ni * 16 + col;
      #pragma unroll
      for (int r = 0; r < 4; ++r) {
        int qglob = qbase + rq + r;
        float ab = (qglob < CL && kglob < CL) ? slope * fabsf((float)(kglob - qglob)) : 0.0f;
        sacc[ni][r] += ab;
        pmax[r] = fmaxf(pmax[r], sacc[ni][r]);
      }
    }
    #pragma unroll
    for (int off = 1; off < 16; off <<= 1)
      #pragma unroll
      for (int r = 0; r < 4; ++r)
        pmax[r] = fmaxf(pmax[r], __shfl_xor(pmax[r], off, 64));
    float alpha[4], psum[4];
    #pragma unroll
    for (int r = 0; r < 4; ++r) {
      float mnew = fmaxf(mrow[r], pmax[r]);
      alpha[r] = __expf(mrow[r] - mnew);
      mrow[r] = mnew;
      psum[r] = 0.0f;
    }
    #pragma unroll
    for (int ni = 0; ni < 4; ++ni)
      #pragma unroll
      for (int r = 0; r < 4; ++r) {
        float pv = __expf(sacc[ni][r] - mrow[r]);
        psum[r] += pv;
        Psw[(rq + r) * 72 + ni * 16 + col] = f2bf(pv);
      }
    #pragma unroll
    for (int off = 1; off < 16; off <<= 1)
      #pragma unroll
      for (int r = 0; r < 4; ++r)
        psum[r] += __shfl_xor(psum[r], off, 64);
    #pragma unroll
    for (int r = 0; r < 4; ++r) lrow[r] = alpha[r] * lrow[r] + psum[r];
    #pragma unroll
    for (int ni = 0; ni < 4; ++ni)
      #pragma unroll
      for (int r = 0; r < 4; ++r) Oacc[ni][r] *= alpha[r];
    bf16x8 pf0 = *(const bf16x8*)(Psw + col * 72 + grp * 8);
    bf16x8 pf1 = *(const bf16x8*)(Psw + col * 72 + 32 + grp * 8);
    #pragma unroll
    for (int ni = 0; ni < 4; ++ni) {
      const us* vp = Vs + (ni * 16 + col) * 72 + grp * 8;
      bf16x8 vf0 = *(const bf16x8*)(vp);
      bf16x8 vf1 = *(const bf16x8*)(vp + 32);
      Oacc[ni] = __builtin_amdgcn_mfma_f32_16x16x32_bf16(pf0, vf0, Oacc[ni], 0, 0, 0);
      Oacc[ni] = __builtin_amdgcn_mfma_f32_16x16x32_bf16(pf1, vf1, Oacc[ni], 0, 0, 0);
    }
  }
  #pragma unroll
  for (int ni = 0; ni < 4; ++ni)
    #pragma unroll
    for (int r = 0; r < 4; ++r) {
      size_t token = (size_t)b * TT + qbase + rq + r;
      obf[token * DDIM + h * 64 + ni * 16 + col] = f2bf(Oacc[ni][r] / lrow[r]);
    }
}

// ---------------- LayerNorm (gain only, eps=1e-5), fp32 or bf16 out ----------------
template<int BF16OUT>
__global__ __launch_bounds__(256)
void ln_kernel(const float* __restrict__ x, const float* __restrict__ g,
               float* outf, us* outb) {
  __shared__ float red[256];
  const int rowi = blockIdx.x, t = threadIdx.x;
  const float* xr = x + (size_t)rowi * DDIM;
  float4 v = ((const float4*)xr)[t];
  red[t] = v.x + v.y + v.z + v.w;
  __syncthreads();
  for (int off = 128; off > 0; off >>= 1) {
    if (t < off) red[t] += red[t + off];
    __syncthreads();
  }
  float mu = red[0] * (1.0f / 1024.0f);
  __syncthreads();
  float dx = v.x - mu, dy = v.y - mu, dz = v.z - mu, dw = v.w - mu;
  red[t] = dx * dx + dy * dy + dz * dz + dw * dw;
  __syncthreads();
  for (int off = 128; off > 0; off >>= 1) {
    if (t < off) red[t] += red[t + off];
    __syncthreads();
  }
  float rs = rsqrtf(red[0] * (1.0f / 1024.0f) + 1e-5f);
  float4 gg = ((const float4*)g)[t];
  if (BF16OUT) {
    usx4 o;
    o.x = f2bf(dx * rs * gg.x); o.y = f2bf(dy * rs * gg.y);
    o.z = f2bf(dz * rs * gg.z); o.w = f2bf(dw * rs * gg.w);
    ((usx4*)(outb + (size_t)rowi * DDIM))[t] = o;
  } else {
    float4 o;
    o.x = dx * rs * gg.x; o.y = dy * rs * gg.y; o.z = dz * rs * gg.z; o.w = dw * rs * gg.w;
    ((float4*)(outf + (size_t)rowi * DDIM))[t] = o;
  }
}

// ---------------- concat [x, s*2^-0.5] -> bf16 [NT, 2048] ----------------
__global__ void concat_cast_kernel(const float* __restrict__ x, const float* __restrict__ s,
                                   us* __restrict__ out) {
  int i4 = blockIdx.x * blockDim.x + threadIdx.x;  // 1048576 threads
  int e = i4 * 4;
  int r = e >> 11, c = e & 2047;
  float4 v;
  if (c < DDIM) {
    v = *(const float4*)(x + (size_t)r * DDIM + c);
  } else {
    v = *(const float4*)(s + (size_t)r * DDIM + (c - DDIM));
    v.x *= 0.70710678118654752f; v.y *= 0.70710678118654752f;
    v.z *= 0.70710678118654752f; v.w *= 0.70710678118654752f;
  }
  usx4 o; o.x = f2bf(v.x); o.y = f2bf(v.y); o.z = f2bf(v.z); o.w = f2bf(v.w);
  ((usx4*)out)[i4] = o;
}

// ---------------- launch ----------------
extern "C" void kernel_launch(void* const* d_in, const int* in_sizes, int n_in,
                              void* d_out, int out_size, void* d_ws, size_t ws_size,
                              hipStream_t stream) {
  (void)in_sizes; (void)n_in; (void)out_size; (void)ws_size;
  const float* x_in       = (const float*)d_in[0];
  const float* attn_w     = (const float*)d_in[1];
  const float* attn_out_w = (const float*)d_in[2];
  const float* mlp_ln_g   = (const float*)d_in[3];
  const float* mlp_in_w   = (const float*)d_in[4];
  const float* mlp_in_b   = (const float*)d_in[5];
  const float* mlp_out_w  = (const float*)d_in[6];
  const float* mlp_out_b  = (const float*)d_in[7];
  const float* skip_w     = (const float*)d_in[8];
  const float* skip_b     = (const float*)d_in[9];
  const float* out_ln_g   = (const float*)d_in[10];

  char* p = (char*)d_ws;
  auto alloc = [&](size_t bytes) { char* r = p; p += (bytes + 255) & ~(size_t)255; return r; };
  float* xbuf = (float*)alloc((size_t)NT * DDIM * 4);
  float* conn = (float*)alloc((size_t)3 * NT * DDIM * 4);
  us* Qb   = (us*)alloc((size_t)NT * DDIM * 2);
  us* Kb   = (us*)alloc((size_t)NT * DDIM * 2);
  us* Vt   = (us*)alloc((size_t)NT * DDIM * 2);
  us* xbf  = (us*)alloc((size_t)NT * DDIM * 2);
  us* obf  = (us*)alloc((size_t)NT * DDIM * 2);
  us* hln  = (us*)alloc((size_t)NT * DDIM * 2);
  us* hbf  = (us*)alloc((size_t)NT * FF * 2);
  us* xcbf = (us*)alloc((size_t)NT * 2 * DDIM * 2);
  us* wqkv = (us*)alloc((size_t)3 * DDIM * DDIM * 2);
  us* wao  = (us*)alloc((size_t)DDIM * DDIM * 2);
  us* wmi  = (us*)alloc((size_t)FF * DDIM * 2);
  us* wmo  = (us*)alloc((size_t)DDIM * FF * 2);
  us* wsk  = (us*)alloc((size_t)DDIM * 2 * DDIM * 2);

  hipMemcpyAsync(xbuf, x_in, (size_t)NT * DDIM * 4, hipMemcpyDeviceToDevice, stream);

  for (int i = 0; i < 8; ++i) {
    const int do_skip = (i >= 5);
    cast5_kernel<<<1024, 256, 0, stream>>>(
        attn_w + (size_t)i * 3 * DDIM * DDIM, wqkv, 3 * DDIM * DDIM / 4,
        attn_out_w + (size_t)i * DDIM * DDIM, wao, DDIM * DDIM / 4,
        mlp_in_w + (size_t)i * FF * DDIM, wmi, FF * DDIM / 4,
        mlp_out_w + (size_t)i * DDIM * FF, wmo, DDIM * FF / 4,
        do_skip ? (skip_w + (size_t)(i - 4) * DDIM * 2 * DDIM) : nullptr, wsk,
        do_skip ? (DDIM * 2 * DDIM / 4) : 0);
    if (do_skip) {
      concat_cast_kernel<<<4096, 256, 0, stream>>>(xbuf, conn + (size_t)(7 - i) * NT * DDIM, xcbf);
      bias_rows_kernel<1><<<NT, 256, 0, stream>>>(xbuf, skip_b + (size_t)(i - 4) * DDIM);
      gemm4<6><<<dim3(8, 32, 2), 256, 0, stream>>>(
          xcbf, wsk, nullptr, xbuf, nullptr, nullptr, nullptr, nullptr,
          NT, DDIM, 2 * DDIM, DDIM);
    }
    cast1_kernel<<<1024, 256, 0, stream>>>(xbuf, xbf, NT * DDIM / 4);
    gemm4<5><<<dim3(24, 32, 1), 256, 0, stream>>>(
        xbf, wqkv, nullptr, nullptr, nullptr, Qb, Kb, Vt,
        NT, 3 * DDIM, DDIM, DDIM);
    attn_mfma_kernel<<<dim3(TT / 64, 2 * NH), 256, 0, stream>>>(Qb, Kb, Vt, obf);
    gemm4<6><<<dim3(8, 32, 2), 256, 0, stream>>>(
        obf, wao, nullptr, xbuf, nullptr, nullptr, nullptr, nullptr,
        NT, DDIM, DDIM, DDIM / 2);
    ln_kernel<1><<<NT, 256, 0, stream>>>(xbuf, mlp_ln_g + (size_t)i * DDIM, nullptr, hln);
    gemm4<2><<<dim3(32, 32, 1), 256, 0, stream>>>(
        hln, wmi, mlp_in_b + (size_t)i * FF, nullptr, hbf, nullptr, nullptr, nullptr,
        NT, FF, DDIM, DDIM);
    bias_rows_kernel<0><<<NT, 256, 0, stream>>>(xbuf, mlp_out_b + (size_t)i * DDIM);
    gemm4<6><<<dim3(8, 32, 4), 256, 0, stream>>>(
        hbf, wmo, nullptr, xbuf, nullptr, nullptr, nullptr, nullptr,
        NT, DDIM, FF, DDIM);
    if (i >= 2 && i <= 4)
      hipMemcpyAsync(conn + (size_t)(i - 2) * NT * DDIM, xbuf, (size_t)NT * DDIM * 4,
                     hipMemcpyDeviceToDevice, stream);
  }
  ln_kernel<0><<<NT, 256, 0, stream>>>(xbuf, out_ln_g, (float*)d_out, nullptr);
}